// Round 1
// baseline (80.708 us; speedup 1.0000x reference)
//
#include <hip/hip_runtime.h>
#include <math.h>
#include <float.h>

#define EPS 1e-6f
#define THRESHOLD 0.5f

#define NB 16
#define NPOLY 16
#define NVERT 200
#define NSEG_PER_POLY 199
#define NSEG (NPOLY * NSEG_PER_POLY)   // 3184 segments per batch
#define NPTB 300                       // points per batch (10 agents * 30)
#define HPTB 150                       // points handled per thread-slot (2 pts/thread)
#define NPOINTS 4800                   // 16 * 300
#define NSLICE 64
#define SEG_PER_SLICE 50               // slices 0..62: 50 segs, slice 63: 34 (both even)

// ---------------------------------------------------------------------------
// R7: LDS-issue-pipe theory. Per-CU ds_read time (20 waves x 100 reads x ~12cy
// = 24k cy) exceeded per-SIMD VALU time (~10.5k cy) in the R5 structure ->
// amortize each wave-uniform segment read over TWO points per thread.
//  * block 320 -> 192 threads; threads 0..149 own points lp and lp+150.
//  * per loop iter: load 2 segments once, apply to both points (4 indep chains)
//    -> total ds_read instrs 512k -> 307k (1.67x fewer).
//  * crossing fast path slimmed: diff = q - v1x with widened band
//    err = 2e-6*|q| + (1e-6*|sx| + 1e-30)  (>= old 1e-6*(|q|+|ixa|) band since
//    |ixa| <= |q|+|sx|); borderline cases still take the bit-exact IEEE-div
//    fallback, which recomputes slope_eps = evy/(evx+EPS)+EPS identically to
//    the prologue (bit-exact, since both are default IEEE ops).
//  * point loads hoisted above the barrier (latency hides under prologue).
// Exactness: cond_y XOR-form exact; distance path (inv_esq/fma/med3) is
// ulp-tolerant (feeds min-dist only); crossing integer path exact via band +
// exact-div fallback.
// ---------------------------------------------------------------------------

struct Seg { float sx, sy, evx, evy, inv_esq, errS, inv_slope, ey; };

__global__ __launch_bounds__(192) void seg_kernel(
    const float* __restrict__ points,
    const float* __restrict__ polys,
    float2* __restrict__ part,        // [NSLICE][NPOINTS]
    float* __restrict__ out)
{
    __shared__ float4 lds[SEG_PER_SLICE * 2];

    const int slice = blockIdx.x;       // 0..63
    const int b     = blockIdx.y;       // 0..15
    const int lp    = threadIdx.x;      // 0..191; 0..149 handle 2 points each

    const int s0 = slice * SEG_PER_SLICE;
    const int s1 = (s0 + SEG_PER_SLICE < NSEG) ? s0 + SEG_PER_SLICE : NSEG;
    const int nseg = s1 - s0;           // 50 or 34 (both even)

    // ---- hoisted point loads: issue before the barrier so HBM latency
    //      overlaps the segment prologue ----
    const int p0i = b * NPTB + (lp < HPTB ? lp : 0);
    const float2 pt0 = ((const float2*)points)[p0i];
    const float2 pt1 = ((const float2*)points)[p0i + HPTB];

    // ---- prologue: per-segment precompute into LDS ----
    if (lp < nseg) {
        const int s = s0 + lp;
        const int m = s / NSEG_PER_POLY;
        const int v = s % NSEG_PER_POLY;
        const float2* poly = (const float2*)polys + ((size_t)(b * NPOLY + m) * NVERT);
        const float2 S = poly[v];
        const float2 E = poly[v + 1];
        const float evx = E.x - S.x;
        const float evy = E.y - S.y;
        const float esq = evx * evx + evy * evy;
        const float inv_esq = 1.0f / (esq + EPS);
        const float slope_eps = evy / (evx + EPS) + EPS;  // exact IEEE, ref order
        const float inv_slope = __builtin_amdgcn_rcpf(slope_eps);
        const float errS = fmaf(fabsf(S.x), 1e-6f, 1e-30f);
        lds[lp * 2]     = make_float4(S.x, S.y, evx, evy);
        lds[lp * 2 + 1] = make_float4(inv_esq, errS, inv_slope, E.y);
    }
    __syncthreads();

    const float px0 = pt0.x, py0 = pt0.y;
    const float px1 = pt1.x, py1 = pt1.y;

    float mnA0 = FLT_MAX, mnB0 = FLT_MAX, mnA1 = FLT_MAX, mnB1 = FLT_MAX;
    int   crA0 = 0,       crB0 = 0,       crA1 = 0,       crB1 = 0;

    auto body = [&](const Seg& g, float px, float py, float& mn, int& cr) {
        // ---- point-to-segment squared distance (ulp-tolerant path) ----
        const float v1x = px - g.sx;
        const float v1y = py - g.sy;
        const float dot = fmaf(v1y, g.evy, v1x * g.evx);
        const float t   = __builtin_amdgcn_fmed3f(dot * g.inv_esq, 0.0f, 1.0f);
        const float dx  = fmaf(-g.evx, t, v1x);
        const float dy  = fmaf(-g.evy, t, v1y);
        mn = fminf(mn, fmaf(dy, dy, dx * dx));

        // ---- even-odd crossing: rcp fast path + exact-div fallback ----
        const bool cond_y = (g.sy <= py) != (g.ey <= py);   // exact
        const float q    = v1y * g.inv_slope;               // ~2 ulp (rcp+mul)
        const float diff = q - v1x;        // sign == ref's (sx+q)>px outside band
        const float err  = fmaf(fabsf(q), 2e-6f, g.errS);   // >= old validated band
        bool left = diff > 0.0f;
        if (cond_y && !(fabsf(diff) > err)) {
            // rare: decision within rcp noise — replicate ref bit-exactly
            const float se = g.evy / (g.evx + EPS) + EPS;   // == prologue slope_eps
            left = (g.sx + v1y / se) > px;
        }
        cr += (cond_y && left) ? 1 : 0;
    };

    auto ldseg = [&](int j) {
        const float4 a = lds[j * 2];        // wave-uniform -> broadcast
        const float4 c = lds[j * 2 + 1];
        return Seg{a.x, a.y, a.z, a.w, c.x, c.y, c.z, c.w};
    };

    // nseg even (50 or 34): 2 segments x 2 points = 4 independent chains/iter
    for (int j = 0; j < nseg; j += 2) {
        const Seg gA = ldseg(j);
        const Seg gB = ldseg(j + 1);
        body(gA, px0, py0, mnA0, crA0);
        body(gA, px1, py1, mnA1, crA1);
        body(gB, px0, py0, mnB0, crB0);
        body(gB, px1, py1, mnB1, crB1);
    }

    if (lp < HPTB) {
        part[slice * NPOINTS + p0i] =
            make_float2(fminf(mnA0, mnB0), __int_as_float(crA0 + crB0));
        part[slice * NPOINTS + p0i + HPTB] =
            make_float2(fminf(mnA1, mnB1), __int_as_float(crA1 + crB1));
    } else if (slice == 0 && lp < HPTB + 10) {
        // zero out[] (poisoned 0xAA); final_kernel atomics run after seg
        // completes (stream order) — race-free.
        out[b * 10 + (lp - HPTB)] = 0.0f;
    }
}

// ---------------------------------------------------------------------------
// Per-point reduction over 64 slices + epilogue + atomic into out.
// ---------------------------------------------------------------------------
__global__ __launch_bounds__(256) void final_kernel(
    const float2* __restrict__ part,
    float* __restrict__ out)
{
    const int p = blockIdx.x * 256 + threadIdx.x;
    if (p >= NPOINTS) return;

    float md = FLT_MAX;
    int c = 0;
    #pragma unroll 16
    for (int k = 0; k < NSLICE; ++k) {
        const float2 pr = part[k * NPOINTS + p];
        md = fminf(md, pr.x);
        c += __float_as_int(pr.y);
    }

    float d = sqrtf(fmaxf(md, EPS));
    if (c & 1) d = -d;
    const float val = fmaxf(d + THRESHOLD, 0.0f);

    const int b = p / NPTB;
    const int a = (p % NPTB) / 30;
    atomicAdd(out + b * 10 + a, val);
}

extern "C" void kernel_launch(void* const* d_in, const int* in_sizes, int n_in,
                              void* d_out, int out_size, void* d_ws, size_t ws_size,
                              hipStream_t stream) {
    const float* points = (const float*)d_in[0];   // (16,10,30,2)
    const float* polys  = (const float*)d_in[1];   // (16,16,200,2)
    float* out = (float*)d_out;                    // (16,10)

    float2* part = (float2*)d_ws;                  // 64*4800*8 B = 2.4 MB

    dim3 grid(NSLICE, NB);                         // 64 x 16 = 1024 blocks
    seg_kernel<<<grid, 192, 0, stream>>>(points, polys, part, out);
    final_kernel<<<(NPOINTS + 255) / 256, 256, 0, stream>>>(part, out);
}